// Round 10
// baseline (624.034 us; speedup 1.0000x reference)
//
#include <hip/hip_runtime.h>
#include <hip/hip_bf16.h>

#define B 6
#define S 1024
#define H 12
#define DK 64
#define DM 768
#define M (B*S)      // 6144
#define BH (B*H)     // 72

typedef __bf16 bf16;
typedef __attribute__((ext_vector_type(8))) __bf16 bf16x8;
typedef __attribute__((ext_vector_type(4))) float f32x4;

#define MFMA __builtin_amdgcn_mfma_f32_16x16x32_bf16
#define SFENCE() __builtin_amdgcn_sched_barrier(0)
#define WAITV(N) asm volatile("s_waitcnt vmcnt(" #N ")" ::: "memory")
#define BARRIER() __builtin_amdgcn_s_barrier()

// async global->LDS, 16B per lane; LDS dst = wave-uniform base + lane*16
__device__ __forceinline__ void gl16(const void* g, void* l) {
  __builtin_amdgcn_global_load_lds(
      (const __attribute__((address_space(1))) unsigned int*)g,
      (__attribute__((address_space(3))) unsigned int*)l, 16, 0, 0);
}

// ---------------- prep: input f32->bf16 convert (z<3) + weight transpose (z>=3)
__global__ void k_prep(const float* __restrict__ Q, const float* __restrict__ K,
                       const float* __restrict__ V,
                       const float* __restrict__ Wq, const float* __restrict__ Wk,
                       const float* __restrict__ Wv, const float* __restrict__ Wo,
                       bf16* __restrict__ xb, bf16* __restrict__ wt) {
  int z = blockIdx.y;
  if (z < 3) {
    const float* X = z==0?Q : z==1?K : V;
    size_t i = ((size_t)blockIdx.x*256 + threadIdx.x)*8;
    float4 a = *(const float4*)(X + i);
    float4 b = *(const float4*)(X + i + 4);
    bf16x8 r;
    r[0]=(bf16)a.x; r[1]=(bf16)a.y; r[2]=(bf16)a.z; r[3]=(bf16)a.w;
    r[4]=(bf16)b.x; r[5]=(bf16)b.y; r[6]=(bf16)b.z; r[7]=(bf16)b.w;
    *(bf16x8*)(xb + (size_t)z*M*DM + i) = r;
  } else {
    int zz = z - 3;
    const float* W = zz==0?Wq : zz==1?Wk : zz==2?Wv : Wo;
    int idx = blockIdx.x*256 + threadIdx.x;   // 0..768*768-1
    int k = idx / DM, n = idx % DM;
    wt[(size_t)zz*DM*DM + (size_t)n*DM + k] = (bf16)W[idx];
  }
}

// ======== GEMM bodies: 128x128 tile, BK=32, 3-deep LDS via global_load_lds ====
// LDS tile [128 rows][4 chunks of 16B]; chunk c holds source chunk c^((row>>1)&3).
// gl16 dst is linear (base + lane*16); swizzle pre-applied on the global source.

// ---------------- QKV projection; epilogue scatters q/k/v (kb,vt pre-swizzled)
__global__ __launch_bounds__(256, 3) void k_proj(
    const bf16* __restrict__ xb, const bf16* __restrict__ wt,
    const float* __restrict__ bq, const float* __restrict__ bk,
    const float* __restrict__ bv,
    bf16* __restrict__ qb, bf16* __restrict__ kb, bf16* __restrict__ vt) {
  int z = blockIdx.z;
  const bf16* X    = xb + (size_t)z*M*DM;
  const float* bias = z==0?bq : z==1?bk : bv;
  const bf16* Wt = wt + (size_t)z*DM*DM;
  int tid = threadIdx.x, lane = tid & 63, w = tid >> 6;
  int wr = w >> 1, wc = w & 1;
  int lr = lane & 15, lg = lane >> 4;
  int m0 = blockIdx.x*128;
  int n0 = blockIdx.y*128;

  __shared__ bf16 As[3][4096];
  __shared__ bf16 Bs[3][4096];
  char* AsL = (char*)&As[0][0];
  char* BsL = (char*)&Bs[0][0];

  // staging: chunk d1 = tid (rows 0..63), d2 = tid+256 (rows 64..127)
  const int r1 = tid >> 2, p1 = tid & 3;
  const int s1 = p1 ^ ((r1 >> 1) & 3);      // same for r2 = r1+64
  const bf16* a1 = X  + (size_t)(m0 + r1)*DM      + s1*8;
  const bf16* a2 = X  + (size_t)(m0 + r1 + 64)*DM + s1*8;
  const bf16* b1 = Wt + (size_t)(n0 + r1)*DM      + s1*8;
  const bf16* b2 = Wt + (size_t)(n0 + r1 + 64)*DM + s1*8;
  const int ldsOff = w*1024;                // + buf*8192 (+4096 for d2)

  const int fs = (lr >> 1) & 3;
  const int fchunk = (lg ^ fs) * 8;

  f32x4 acc[4][4];
  #pragma unroll
  for (int i=0;i<4;++i)
    #pragma unroll
    for (int j=0;j<4;++j) acc[i][j] = (f32x4){0.f,0.f,0.f,0.f};

  // prologue: stage tiles 0,1
  #pragma unroll
  for (int tt = 0; tt < 2; ++tt) {
    gl16(a1 + tt*32, AsL + tt*8192 + ldsOff);
    gl16(a2 + tt*32, AsL + tt*8192 + 4096 + ldsOff);
    gl16(b1 + tt*32, BsL + tt*8192 + ldsOff);
    gl16(b2 + tt*32, BsL + tt*8192 + 4096 + ldsOff);
  }
  SFENCE();
  WAITV(4);      // L(0) done (L(1)'s 4 may remain)
  BARRIER();
  SFENCE();

  int cur = 0, nb = 2;
  for (int t = 0; t < 24; ++t) {
    const bf16* Ac = (const bf16*)(AsL + cur*8192);
    const bf16* Bc = (const bf16*)(BsL + cur*8192);
    if (t < 22) {
      int k0 = (t+2)*32;
      gl16(a1 + k0, AsL + nb*8192 + ldsOff);
      gl16(a2 + k0, AsL + nb*8192 + 4096 + ldsOff);
      gl16(b1 + k0, BsL + nb*8192 + ldsOff);
      gl16(b2 + k0, BsL + nb*8192 + 4096 + ldsOff);
    }
    SFENCE();
    bf16x8 af[4], bfr[4];
    __builtin_amdgcn_s_setprio(1);
    #pragma unroll
    for (int mi=0;mi<4;++mi) af[mi]  = *(const bf16x8*)&Ac[(wr*64 + mi*16 + lr)*32 + fchunk];
    #pragma unroll
    for (int ni=0;ni<4;++ni) bfr[ni] = *(const bf16x8*)&Bc[(wc*64 + ni*16 + lr)*32 + fchunk];
    #pragma unroll
    for (int mi=0;mi<4;++mi)
      #pragma unroll
      for (int ni=0;ni<4;++ni)
        acc[mi][ni] = MFMA(af[mi], bfr[ni], acc[mi][ni], 0,0,0);
    __builtin_amdgcn_s_setprio(0);
    SFENCE();
    if (t < 23) {
      if (t < 22) { WAITV(4); } else { WAITV(0); }
      BARRIER();
      SFENCE();
    }
    cur = (cur==2)?0:cur+1;
    nb  = (nb==2)?0:nb+1;
  }

  int mw = m0 + wr*64, nw = n0 + wc*64;
  #pragma unroll
  for (int ni=0;ni<4;++ni) {
    int n = nw + ni*16 + lr;
    float bs = bias[n];
    int h = n >> 6, d = n & 63;
    #pragma unroll
    for (int mi=0;mi<4;++mi)
      #pragma unroll
      for (int r=0;r<4;++r) {
        int m = mw + mi*16 + lg*4 + r;
        int bb = m >> 10, s = m & 1023;
        float val = acc[mi][ni][r] + bs;
        if (z == 0) {
          qb[((size_t)(bb*H + h)*S + s)*DK + d] = (bf16)val;
        } else if (z == 1) {
          int dsw = ((((d>>3) ^ (s&7))) << 3) | (d&7);          // slot ^= s&7
          kb[((size_t)(bb*H + h)*S + s)*DK + dsw] = (bf16)val;
        } else {
          int ssw = (s & ~63) | ((((s&63)>>3) ^ (d&7)) << 3) | (s&7); // slot ^= d&7
          vt[((size_t)(bb*H + h)*DK + d)*S + ssw] = (bf16)val;
        }
      }
  }
}

// ---------------- out projection + bias + residual -> x (f32), same tiled body
__global__ __launch_bounds__(256, 3) void k_oproj(
    const bf16* __restrict__ ctx, const bf16* __restrict__ wto,
    const float* __restrict__ bo, const float* __restrict__ res,
    float* __restrict__ x) {
  int tid = threadIdx.x, lane = tid & 63, w = tid >> 6;
  int wr = w >> 1, wc = w & 1;
  int lr = lane & 15, lg = lane >> 4;
  int m0 = blockIdx.x*128;
  int n0 = blockIdx.y*128;

  __shared__ bf16 As[3][4096];
  __shared__ bf16 Bs[3][4096];
  char* AsL = (char*)&As[0][0];
  char* BsL = (char*)&Bs[0][0];

  const int r1 = tid >> 2, p1 = tid & 3;
  const int s1 = p1 ^ ((r1 >> 1) & 3);
  const bf16* a1 = ctx + (size_t)(m0 + r1)*DM      + s1*8;
  const bf16* a2 = ctx + (size_t)(m0 + r1 + 64)*DM + s1*8;
  const bf16* b1 = wto + (size_t)(n0 + r1)*DM      + s1*8;
  const bf16* b2 = wto + (size_t)(n0 + r1 + 64)*DM + s1*8;
  const int ldsOff = w*1024;

  const int fs = (lr >> 1) & 3;
  const int fchunk = (lg ^ fs) * 8;

  f32x4 acc[4][4];
  #pragma unroll
  for (int i=0;i<4;++i)
    #pragma unroll
    for (int j=0;j<4;++j) acc[i][j] = (f32x4){0.f,0.f,0.f,0.f};

  #pragma unroll
  for (int tt = 0; tt < 2; ++tt) {
    gl16(a1 + tt*32, AsL + tt*8192 + ldsOff);
    gl16(a2 + tt*32, AsL + tt*8192 + 4096 + ldsOff);
    gl16(b1 + tt*32, BsL + tt*8192 + ldsOff);
    gl16(b2 + tt*32, BsL + tt*8192 + 4096 + ldsOff);
  }
  SFENCE();
  WAITV(4);
  BARRIER();
  SFENCE();

  int cur = 0, nb = 2;
  for (int t = 0; t < 24; ++t) {
    const bf16* Ac = (const bf16*)(AsL + cur*8192);
    const bf16* Bc = (const bf16*)(BsL + cur*8192);
    if (t < 22) {
      int k0 = (t+2)*32;
      gl16(a1 + k0, AsL + nb*8192 + ldsOff);
      gl16(a2 + k0, AsL + nb*8192 + 4096 + ldsOff);
      gl16(b1 + k0, BsL + nb*8192 + ldsOff);
      gl16(b2 + k0, BsL + nb*8192 + 4096 + ldsOff);
    }
    SFENCE();
    bf16x8 af[4], bfr[4];
    __builtin_amdgcn_s_setprio(1);
    #pragma unroll
    for (int mi=0;mi<4;++mi) af[mi]  = *(const bf16x8*)&Ac[(wr*64 + mi*16 + lr)*32 + fchunk];
    #pragma unroll
    for (int ni=0;ni<4;++ni) bfr[ni] = *(const bf16x8*)&Bc[(wc*64 + ni*16 + lr)*32 + fchunk];
    #pragma unroll
    for (int mi=0;mi<4;++mi)
      #pragma unroll
      for (int ni=0;ni<4;++ni)
        acc[mi][ni] = MFMA(af[mi], bfr[ni], acc[mi][ni], 0,0,0);
    __builtin_amdgcn_s_setprio(0);
    SFENCE();
    if (t < 23) {
      if (t < 22) { WAITV(4); } else { WAITV(0); }
      BARRIER();
      SFENCE();
    }
    cur = (cur==2)?0:cur+1;
    nb  = (nb==2)?0:nb+1;
  }

  int mw = m0 + wr*64, nw = n0 + wc*64;
  #pragma unroll
  for (int ni=0;ni<4;++ni) {
    int n = nw + ni*16 + lr;
    float bb = bo[n];
    #pragma unroll
    for (int mi=0;mi<4;++mi)
      #pragma unroll
      for (int r=0;r<4;++r) {
        int m = mw + mi*16 + lg*4 + r;
        x[(size_t)m*DM + n] = acc[mi][ni][r] + bb + res[(size_t)m*DM + n];
      }
  }
}

__device__ __forceinline__ unsigned pk2(float a, float b) {
  union { bf16 h[2]; unsigned u; } x;
  x.h[0] = (bf16)a; x.h[1] = (bf16)b;
  return x.u;
}

// ---------------- fused attention: SINGLE pass, deferred normalization.
// Block = (bh, 64 q-rows), 4 waves x 16 rows. K double-buffered in LDS (gl16);
// V read direct from L2 (reg-prefetched 1 iter ahead, A/B unrolled); mask prefetched.
// Writes UNNORMALIZED exp(s) to attn, accumulates row-sum + PV; epilogue rescales
// cacc (via 4 shuffles: inv lives at lane lr, acc rows are lg*4+r) and rescales
// attn in place (same-wave re-read after vmcnt(0) -- L2-hot).
#define FITER(T, P, VC, VN, MC, MN)                                           \
  {                                                                           \
    const bf16* Kc = (const bf16*)(KbL + (P)*8192);                           \
    if ((T) < 15) {                                                           \
      gl16(ksrc + ((T)+1)*8192,        KbL + ((P)^1)*8192 + ldsK);            \
      gl16(ksrc + ((T)+1)*8192 + 1024, KbL + ((P)^1)*8192 + ldsK + 1024);     \
    }                                                                         \
    SFENCE();                                                                 \
    if ((T) < 15) {                                                           \
      _Pragma("unroll")                                                       \
      for (int j=0;j<8;++j)                                                   \
        VN[j] = *(const bf16x8*)(vg + voff[j] + ((T)+1)*128);                 \
      _Pragma("unroll")                                                       \
      for (int i=0;i<4;++i)                                                   \
        MN[i] = *(const uchar4*)(mrow + ((T)+1)*64 + i*16 + lg*4);            \
    }                                                                         \
    SFENCE();                                                                 \
    __builtin_amdgcn_s_setprio(1);                                            \
    _Pragma("unroll")                                                         \
    for (int u = 0; u < 2; ++u) {                                             \
      _Pragma("unroll")                                                       \
      for (int half = 0; half < 2; ++half) {                                  \
        int i = u*2 + half;                                                   \
        bf16x8 kf0 = *(const bf16x8*)&Kc[i*1024 + kf0o];                      \
        bf16x8 kf1 = *(const bf16x8*)&Kc[i*1024 + kf1o];                      \
        f32x4 sc = {0.f,0.f,0.f,0.f};                                         \
        sc = MFMA(kf0, qa0, sc, 0,0,0);                                       \
        sc = MFMA(kf1, qa1, sc, 0,0,0);                                       \
        float p0 = MC[i].x ? 0.f : __expf(sc[0]*0.125f);                      \
        float p1 = MC[i].y ? 0.f : __expf(sc[1]*0.125f);                      \
        float p2 = MC[i].z ? 0.f : __expf(sc[2]*0.125f);                      \
        float p3 = MC[i].w ? 0.f : __expf(sc[3]*0.125f);                      \
        sum += p0 + p1 + p2 + p3;                                             \
        *(float4*)(abase + (T)*64 + i*16 + lg*4) = (float4){p0,p1,p2,p3};     \
        uint2 pw2; pw2.x = pk2(p0,p1); pw2.y = pk2(p2,p3);                    \
        *(uint2*)(buf + lr*64 + ((half*32 + lg*8) ^ swzP)) = pw2;             \
      }                                                                       \
      bf16x8 pa = *(const bf16x8*)(buf + lr*64 + ((lg*16) ^ swzP));           \
      _Pragma("unroll")                                                       \
      for (int dd=0; dd<4; ++dd)                                              \
        cacc[dd] = MFMA(pa, VC[u*4+dd], cacc[dd], 0,0,0);                     \
    }                                                                         \
    __builtin_amdgcn_s_setprio(0);                                            \
    SFENCE();                                                                 \
    if ((T) < 15) { WAITV(16); BARRIER(); SFENCE(); }                         \
  }

__global__ __launch_bounds__(256, 4) void k_fattn(
    const bf16* __restrict__ qb, const bf16* __restrict__ kb,
    const bf16* __restrict__ vt, const unsigned char* __restrict__ mask,
    float* __restrict__ attn, bf16* __restrict__ ctx) {
  int lin = blockIdx.x + 16*blockIdx.y;   // 0..1151
  int xcd  = lin & 7;
  int slot = lin >> 3;
  int qt   = slot & 15;
  int bh   = xcd*9 + (slot >> 4);         // bijective remap: head locality per XCD
  int b = bh / H, h = bh - b*H;
  int tid = threadIdx.x, lane = tid & 63, w = tid >> 6;
  int lr = lane & 15, lg = lane >> 4;
  int q0 = qt*64 + w*16;

  __shared__ bf16 Kb[2][4096];      // [64 k][64 dk] swizzled, 8KB each
  __shared__ bf16 pt[4][512];       // per-wave P tile, 1KB
  char* KbL = (char*)&Kb[0][0];

  const bf16* qbase = qb + ((size_t)bh*S + q0 + lr)*DK + lg*8;
  bf16x8 qa0 = *(const bf16x8*)(qbase);
  bf16x8 qa1 = *(const bf16x8*)(qbase + 32);
  SFENCE();   // keep q loads out of the counted windows below

  const char* kg = (const char*)(kb + (size_t)bh*S*DK);   // 8KB contiguous per tile
  const char* vg = (const char*)(vt + (size_t)bh*DK*S);   // rows 2048B apart
  const unsigned char* mrow = mask + ((size_t)b*S + q0 + lr)*S;
  float* abase = attn + ((size_t)bh*S + q0 + lr)*S;

  // K staging (per-lane src; LDS dst = wave-uniform base + lane*16)
  const char* ksrc = kg + w*2048 + lane*16;                // + t*8192
  const int ldsK = w*2048;                                 // + buf*8192

  // V direct-read offsets (global pre-swizzle slot^=d&7 within 128B windows)
  int voff[8];
  #pragma unroll
  for (int u=0;u<2;++u)
    #pragma unroll
    for (int dd=0;dd<4;++dd)
      voff[u*4+dd] = (dd*16+lr)*2048 + ((((u*4+lg) ^ (lr&7))) << 4);

  // K fragment read offsets (bf16 idx), swizzle: slot ^ (row&7)
  const int krow = lr*64;
  const int kf0o = krow + ((lg ^ (lr&7))<<3);
  const int kf1o = krow + (((4+lg) ^ (lr&7))<<3);
  const int swzP = (lr & 3) << 4;

  // ---- prologue: stage K(0); load V(0)/mask(0)
  gl16(ksrc,        KbL + ldsK);
  gl16(ksrc + 1024, KbL + ldsK + 1024);
  SFENCE();
  bf16x8 vnA[8], vnB[8];
  uchar4 mkA[4], mkB[4];
  #pragma unroll
  for (int j=0;j<8;++j) vnA[j] = *(const bf16x8*)(vg + voff[j]);
  #pragma unroll
  for (int i=0;i<4;++i) mkA[i] = *(const uchar4*)(mrow + i*16 + lg*4);
  SFENCE();
  WAITV(12);        // 8 V + 4 mask newer than the 2 K gl16s
  BARRIER();
  SFENCE();

  f32x4 cacc[4];
  #pragma unroll
  for (int d=0;d<4;++d) cacc[d] = (f32x4){0.f,0.f,0.f,0.f};
  float sum = 0.f;
  char* buf = (char*)&pt[w][0];

  for (int tp = 0; tp < 8; ++tp) {
    int t0 = tp*2;
    FITER(t0,   0, vnA, vnB, mkA, mkB);
    FITER(t0+1, 1, vnB, vnA, mkB, mkA);
  }

  // ---- epilogue: row sums -> inv; rescale cacc (shuffle inv to acc rows)
  sum += __shfl_xor(sum, 16);
  sum += __shfl_xor(sum, 32);
  float inv = 1.f / sum;
  float invq[4];
  #pragma unroll
  for (int r=0;r<4;++r) invq[r] = __shfl(inv, lg*4 + r);
  #pragma unroll
  for (int d=0;d<4;++d)
    #pragma unroll
    for (int r=0;r<4;++r)
      ctx[((size_t)b*S + q0 + lg*4 + r)*DM + h*DK + d*16 + lr] =
          (bf16)(cacc[d][r] * invq[r]);

  // ---- rescale attn in place (own stores visible after vmcnt(0); L2-hot)
  asm volatile("s_waitcnt vmcnt(0)" ::: "memory");
  #pragma unroll 2
  for (int t2 = 0; t2 < 16; ++t2) {
    #pragma unroll
    for (int i=0;i<4;++i) {
      float4* p = (float4*)(abase + t2*64 + i*16 + lg*4);
      float4 v = *p;
      v.x*=inv; v.y*=inv; v.z*=inv; v.w*=inv;
      *p = v;
    }
  }
}

// ---------------- layernorm rows of 768 -> d_out
__global__ void k_ln(const float* __restrict__ x, const float* __restrict__ gamma,
                     const float* __restrict__ beta, float* __restrict__ out) {
  int row = blockIdx.x; int tid = threadIdx.x;
  const float* xr = x + (size_t)row*DM;
  float v0 = xr[tid], v1 = xr[tid+256], v2 = xr[tid+512];
  float s = v0+v1+v2, ss = v0*v0+v1*v1+v2*v2;
  #pragma unroll
  for (int off=32; off; off>>=1){ s += __shfl_xor(s,off); ss += __shfl_xor(ss,off); }
  __shared__ float sm[8];
  int w = tid>>6;
  if ((tid&63)==0){ sm[w]=s; sm[4+w]=ss; }
  __syncthreads();
  s = sm[0]+sm[1]+sm[2]+sm[3]; ss = sm[4]+sm[5]+sm[6]+sm[7];
  float mean = s * (1.f/DM);
  float var = ss * (1.f/DM) - mean*mean;
  float rstd = rsqrtf(var + 1e-5f);
  out[(size_t)row*DM + tid]     = (v0-mean)*rstd*gamma[tid]     + beta[tid];
  out[(size_t)row*DM + tid+256] = (v1-mean)*rstd*gamma[tid+256] + beta[tid+256];
  out[(size_t)row*DM + tid+512] = (v2-mean)*rstd*gamma[tid+512] + beta[tid+512];
}

extern "C" void kernel_launch(void* const* d_in, const int* in_sizes, int n_in,
                              void* d_out, int out_size, void* d_ws, size_t ws_size,
                              hipStream_t stream) {
  const float* Q  = (const float*)d_in[0];
  const float* K  = (const float*)d_in[1];
  const float* V  = (const float*)d_in[2];
  const unsigned char* mask = (const unsigned char*)d_in[3];
  const float* Wq = (const float*)d_in[4];
  const float* bq = (const float*)d_in[5];
  const float* Wk = (const float*)d_in[6];
  const float* bk = (const float*)d_in[7];
  const float* Wv = (const float*)d_in[8];
  const float* bv = (const float*)d_in[9];
  const float* Wo = (const float*)d_in[10];
  const float* bo = (const float*)d_in[11];
  const float* gamma = (const float*)d_in[12];
  const float* beta  = (const float*)d_in[13];

  char* ws = (char*)d_ws;
  bf16* wt  = (bf16*)(ws + 0);            // [4][768][768]        4,718,592 B
  bf16* xb  = (bf16*)(ws + 4718592);      // [3][6144][768]      28,311,552 B
  bf16* qb  = (bf16*)(ws + 33030144);     // [72][1024][64]       9,437,184 B
  bf16* kb  = (bf16*)(ws + 42467328);     // [72][1024][64] swz   9,437,184 B
  bf16* vt  = (bf16*)(ws + 51904512);     // [72][64][1024] swz   9,437,184 B
  bf16* ctx = (bf16*)(ws + 61341696);     // [6][1024][768]       9,437,184 B
  float* x  = (float*)(ws + 4718592);     // alias xb (dead after k_proj)

  float* out  = (float*)d_out;                   // [6][1024][768]
  float* attn = out + (size_t)B*S*DM;            // [6][12][1024][1024]

  k_prep  <<<dim3(2304,7),  256, 0, stream>>>(Q,K,V,Wq,Wk,Wv,Wo,xb,wt);
  k_proj  <<<dim3(48,6,3),  256, 0, stream>>>(xb,wt,bq,bk,bv,qb,kb,vt);
  k_fattn <<<dim3(16,BH),   256, 0, stream>>>(qb,kb,vt,mask,attn,ctx);
  k_oproj <<<dim3(48,6),    256, 0, stream>>>(ctx, wt + (size_t)3*DM*DM, bo, Q, x);
  k_ln    <<<dim3(M),       256, 0, stream>>>(x,gamma,beta,out);
}

// Round 11
// 382.315 us; speedup vs baseline: 1.6323x; 1.6323x over previous
//
#include <hip/hip_runtime.h>
#include <hip/hip_bf16.h>

#define B 6
#define S 1024
#define H 12
#define DK 64
#define DM 768
#define M (B*S)      // 6144
#define BH (B*H)     // 72

typedef __bf16 bf16;
typedef __attribute__((ext_vector_type(8))) __bf16 bf16x8;
typedef __attribute__((ext_vector_type(4))) float f32x4;

#define MFMA __builtin_amdgcn_mfma_f32_16x16x32_bf16
#define SFENCE() __builtin_amdgcn_sched_barrier(0)
#define WAITV(N) asm volatile("s_waitcnt vmcnt(" #N ")" ::: "memory")
#define BARRIER() __builtin_amdgcn_s_barrier()

// lgkm-only barrier for reg-staged GEMMs
__device__ __forceinline__ void lds_barrier() {
  asm volatile("s_waitcnt lgkmcnt(0)" ::: "memory");
  __builtin_amdgcn_s_barrier();
}

// async global->LDS, 16B per lane; LDS dst = wave-uniform base (+ lane*16 by HW)
__device__ __forceinline__ void gl16(const void* g, void* l) {
  __builtin_amdgcn_global_load_lds(
      (const __attribute__((address_space(1))) unsigned int*)g,
      (__attribute__((address_space(3))) unsigned int*)l, 16, 0, 0);
}

// 0.125 * log2(e): folded into q so softmax exp becomes exp2
#define QSCALE 0.18033688011112042f

// ---------------- prep: input f32->bf16 convert (z<3) + weight transpose (z>=3)
__global__ void k_prep(const float* __restrict__ Q, const float* __restrict__ K,
                       const float* __restrict__ V,
                       const float* __restrict__ Wq, const float* __restrict__ Wk,
                       const float* __restrict__ Wv, const float* __restrict__ Wo,
                       bf16* __restrict__ xb, bf16* __restrict__ wt) {
  int z = blockIdx.y;
  if (z < 3) {
    const float* X = z==0?Q : z==1?K : V;
    size_t i = ((size_t)blockIdx.x*256 + threadIdx.x)*8;
    float4 a = *(const float4*)(X + i);
    float4 b = *(const float4*)(X + i + 4);
    bf16x8 r;
    r[0]=(bf16)a.x; r[1]=(bf16)a.y; r[2]=(bf16)a.z; r[3]=(bf16)a.w;
    r[4]=(bf16)b.x; r[5]=(bf16)b.y; r[6]=(bf16)b.z; r[7]=(bf16)b.w;
    *(bf16x8*)(xb + (size_t)z*M*DM + i) = r;
  } else {
    int zz = z - 3;
    const float* W = zz==0?Wq : zz==1?Wk : zz==2?Wv : Wo;
    int idx = blockIdx.x*256 + threadIdx.x;   // 0..768*768-1
    int k = idx / DM, n = idx % DM;
    wt[(size_t)zz*DM*DM + (size_t)n*DM + k] = (bf16)W[idx];
  }
}

// ---------------- QKV projection: 128x128 tile, BK=32, dbuf LDS, reg-staged
// (round-8 proven version). q output pre-scaled by QSCALE.
__global__ __launch_bounds__(256, 3) void k_proj(
    const bf16* __restrict__ xb, const bf16* __restrict__ wt,
    const float* __restrict__ bq, const float* __restrict__ bk,
    const float* __restrict__ bv,
    bf16* __restrict__ qb, bf16* __restrict__ kb, bf16* __restrict__ vt) {
  int z = blockIdx.z;
  const bf16* X    = xb + (size_t)z*M*DM;
  const float* bias = z==0?bq : z==1?bk : bv;
  const bf16* Wt = wt + (size_t)z*DM*DM;
  int tid = threadIdx.x, lane = tid & 63, w = tid >> 6;
  int wr = w >> 1, wc = w & 1;
  int lr = lane & 15, lg = lane >> 4;
  int m0 = blockIdx.x*128;
  int n0 = blockIdx.y*128;

  __shared__ bf16 As[2][128*32];
  __shared__ bf16 Bs[2][128*32];

  const int srow = tid >> 1;
  const int c0   = (tid & 1) * 2;
  const int f    = (srow >> 1) & 3;
  const int sc   = (c0 ^ f) & ~1;
  const bool sw  = (f & 1);
  const bf16* asrc = X  + (size_t)(m0 + srow)*DM + sc*8;
  const bf16* bsrc = Wt + (size_t)(n0 + srow)*DM + sc*8;
  const int dst0 = srow*32 + c0*8;
  const int fs = (lr >> 1) & 3;
  const int fchunk = (lg ^ fs) * 8;

  f32x4 acc[4][4];
  #pragma unroll
  for (int i=0;i<4;++i)
    #pragma unroll
    for (int j=0;j<4;++j) acc[i][j] = (f32x4){0.f,0.f,0.f,0.f};

  {
    bf16x8 a0 = *(const bf16x8*)(asrc);
    bf16x8 a1 = *(const bf16x8*)(asrc + 8);
    bf16x8 b0 = *(const bf16x8*)(bsrc);
    bf16x8 b1 = *(const bf16x8*)(bsrc + 8);
    *(bf16x8*)&As[0][dst0]     = sw ? a1 : a0;
    *(bf16x8*)&As[0][dst0 + 8] = sw ? a0 : a1;
    *(bf16x8*)&Bs[0][dst0]     = sw ? b1 : b0;
    *(bf16x8*)&Bs[0][dst0 + 8] = sw ? b0 : b1;
  }
  lds_barrier();

  for (int t = 0; t < 24; ++t) {
    int cur = t & 1;
    bf16x8 pa0, pa1, pb0, pb1;
    if (t < 23) {
      int k0 = (t+1)*32;
      pa0 = *(const bf16x8*)(asrc + k0);
      pa1 = *(const bf16x8*)(asrc + k0 + 8);
      pb0 = *(const bf16x8*)(bsrc + k0);
      pb1 = *(const bf16x8*)(bsrc + k0 + 8);
    }
    bf16x8 af[4], bfr[4];
    #pragma unroll
    for (int mi=0;mi<4;++mi) af[mi]  = *(const bf16x8*)&As[cur][(wr*64 + mi*16 + lr)*32 + fchunk];
    #pragma unroll
    for (int ni=0;ni<4;++ni) bfr[ni] = *(const bf16x8*)&Bs[cur][(wc*64 + ni*16 + lr)*32 + fchunk];
    #pragma unroll
    for (int mi=0;mi<4;++mi)
      #pragma unroll
      for (int ni=0;ni<4;++ni)
        acc[mi][ni] = MFMA(af[mi], bfr[ni], acc[mi][ni], 0,0,0);
    if (t < 23) {
      *(bf16x8*)&As[cur^1][dst0]     = sw ? pa1 : pa0;
      *(bf16x8*)&As[cur^1][dst0 + 8] = sw ? pa0 : pa1;
      *(bf16x8*)&Bs[cur^1][dst0]     = sw ? pb1 : pb0;
      *(bf16x8*)&Bs[cur^1][dst0 + 8] = sw ? pb0 : pb1;
      lds_barrier();
    }
  }

  int mw = m0 + wr*64, nw = n0 + wc*64;
  #pragma unroll
  for (int ni=0;ni<4;++ni) {
    int n = nw + ni*16 + lr;
    float bs = bias[n];
    int h = n >> 6, d = n & 63;
    #pragma unroll
    for (int mi=0;mi<4;++mi)
      #pragma unroll
      for (int r=0;r<4;++r) {
        int m = mw + mi*16 + lg*4 + r;
        int bb = m >> 10, s = m & 1023;
        float val = acc[mi][ni][r] + bs;
        if (z == 0) {
          qb[((size_t)(bb*H + h)*S + s)*DK + d] = (bf16)(val * QSCALE);
        } else if (z == 1) {
          int dsw = ((((d>>3) ^ (s&7))) << 3) | (d&7);          // slot ^= s&7
          kb[((size_t)(bb*H + h)*S + s)*DK + dsw] = (bf16)val;
        } else {
          int ssw = (s & ~63) | ((((s&63)>>3) ^ (d&7)) << 3) | (s&7); // slot ^= d&7
          vt[((size_t)(bb*H + h)*DK + d)*S + ssw] = (bf16)val;
        }
      }
  }
}

// ---------------- out projection + bias + residual -> x (f32), round-8 body
__global__ __launch_bounds__(256, 3) void k_oproj(
    const bf16* __restrict__ ctx, const bf16* __restrict__ wto,
    const float* __restrict__ bo, const float* __restrict__ res,
    float* __restrict__ x) {
  int tid = threadIdx.x, lane = tid & 63, w = tid >> 6;
  int wr = w >> 1, wc = w & 1;
  int lr = lane & 15, lg = lane >> 4;
  int m0 = blockIdx.x*128;
  int n0 = blockIdx.y*128;

  __shared__ bf16 As[2][128*32];
  __shared__ bf16 Bs[2][128*32];

  const int srow = tid >> 1;
  const int c0   = (tid & 1) * 2;
  const int f    = (srow >> 1) & 3;
  const int sc   = (c0 ^ f) & ~1;
  const bool sw  = (f & 1);
  const bf16* asrc = ctx + (size_t)(m0 + srow)*DM + sc*8;
  const bf16* bsrc = wto + (size_t)(n0 + srow)*DM + sc*8;
  const int dst0 = srow*32 + c0*8;
  const int fs = (lr >> 1) & 3;
  const int fchunk = (lg ^ fs) * 8;

  f32x4 acc[4][4];
  #pragma unroll
  for (int i=0;i<4;++i)
    #pragma unroll
    for (int j=0;j<4;++j) acc[i][j] = (f32x4){0.f,0.f,0.f,0.f};

  {
    bf16x8 a0 = *(const bf16x8*)(asrc);
    bf16x8 a1 = *(const bf16x8*)(asrc + 8);
    bf16x8 b0 = *(const bf16x8*)(bsrc);
    bf16x8 b1 = *(const bf16x8*)(bsrc + 8);
    *(bf16x8*)&As[0][dst0]     = sw ? a1 : a0;
    *(bf16x8*)&As[0][dst0 + 8] = sw ? a0 : a1;
    *(bf16x8*)&Bs[0][dst0]     = sw ? b1 : b0;
    *(bf16x8*)&Bs[0][dst0 + 8] = sw ? b0 : b1;
  }
  lds_barrier();

  for (int t = 0; t < 24; ++t) {
    int cur = t & 1;
    bf16x8 pa0, pa1, pb0, pb1;
    if (t < 23) {
      int k0 = (t+1)*32;
      pa0 = *(const bf16x8*)(asrc + k0);
      pa1 = *(const bf16x8*)(asrc + k0 + 8);
      pb0 = *(const bf16x8*)(bsrc + k0);
      pb1 = *(const bf16x8*)(bsrc + k0 + 8);
    }
    bf16x8 af[4], bfr[4];
    #pragma unroll
    for (int mi=0;mi<4;++mi) af[mi]  = *(const bf16x8*)&As[cur][(wr*64 + mi*16 + lr)*32 + fchunk];
    #pragma unroll
    for (int ni=0;ni<4;++ni) bfr[ni] = *(const bf16x8*)&Bs[cur][(wc*64 + ni*16 + lr)*32 + fchunk];
    #pragma unroll
    for (int mi=0;mi<4;++mi)
      #pragma unroll
      for (int ni=0;ni<4;++ni)
        acc[mi][ni] = MFMA(af[mi], bfr[ni], acc[mi][ni], 0,0,0);
    if (t < 23) {
      *(bf16x8*)&As[cur^1][dst0]     = sw ? pa1 : pa0;
      *(bf16x8*)&As[cur^1][dst0 + 8] = sw ? pa0 : pa1;
      *(bf16x8*)&Bs[cur^1][dst0]     = sw ? pb1 : pb0;
      *(bf16x8*)&Bs[cur^1][dst0 + 8] = sw ? pb0 : pb1;
      lds_barrier();
    }
  }

  int mw = m0 + wr*64, nw = n0 + wc*64;
  #pragma unroll
  for (int ni=0;ni<4;++ni) {
    int n = nw + ni*16 + lr;
    float bb = bo[n];
    #pragma unroll
    for (int mi=0;mi<4;++mi)
      #pragma unroll
      for (int r=0;r<4;++r) {
        int m = mw + mi*16 + lg*4 + r;
        x[(size_t)m*DM + n] = acc[mi][ni][r] + bb + res[(size_t)m*DM + n];
      }
  }
}

__device__ __forceinline__ unsigned pk2(float a, float b) {
  union { bf16 h[2]; unsigned u; } x;
  x.h[0] = (bf16)a; x.h[1] = (bf16)b;
  return x.u;
}

// ---------------- fused attention: two-pass, KBLK=128, K via gl16 dbuf,
// V direct from L2 (reg A/B prefetch), counted vmcnt, exp2 (q pre-scaled).
// Block = (bh, 64 q-rows), 4 waves x 16 rows.
// Swapped QK^T: mfma(A=K, B=Q) -> lane(lr,lg) holds p[k=lg*4+r][q=lr].

// stage one 16KB K tile (4 gl16 per thread; linear dst, pre-swizzled global src)
#define STAGE_K(T, BUF)                                                        \
  gl16(ksrc + (T)*16384,         KbL + (BUF)*16384 + ldsK);                    \
  gl16(ksrc + (T)*16384 + 4096,  KbL + (BUF)*16384 + ldsK + 4096);             \
  gl16(ksrc + (T)*16384 + 8192,  KbL + (BUF)*16384 + ldsK + 8192);             \
  gl16(ksrc + (T)*16384 + 12288, KbL + (BUF)*16384 + ldsK + 12288);

// one 64-k sub-step of pass 2 (T = 64-k window index 0..15)
#define FSUB(T, KOFF, VC, VN, MC, MN)                                          \
  {                                                                            \
    const bf16* Kt = (const bf16*)(KbL + (KOFF));                              \
    if ((T) < 15) {                                                            \
      _Pragma("unroll")                                                        \
      for (int j=0;j<8;++j) VN[j] = *(const bf16x8*)(vg + voff[j] + ((T)+1)*128); \
      _Pragma("unroll")                                                        \
      for (int i=0;i<4;++i) MN[i] = *(const uchar4*)(mrow + ((T)+1)*64 + i*16 + lg*4); \
    }                                                                          \
    SFENCE();                                                                  \
    __builtin_amdgcn_s_setprio(1);                                             \
    _Pragma("unroll")                                                          \
    for (int u = 0; u < 2; ++u) {                                              \
      _Pragma("unroll")                                                        \
      for (int hf = 0; hf < 2; ++hf) {                                         \
        int i = u*2 + hf;                                                      \
        bf16x8 kf0 = *(const bf16x8*)&Kt[i*1024 + kf0o];                       \
        bf16x8 kf1 = *(const bf16x8*)&Kt[i*1024 + kf1o];                       \
        f32x4 sc = {0.f,0.f,0.f,0.f};                                          \
        sc = MFMA(kf0, qa0, sc, 0,0,0);                                        \
        sc = MFMA(kf1, qa1, sc, 0,0,0);                                        \
        float p0 = MC[i].x ? 0.f : exp2f(sc[0])*inv;                           \
        float p1 = MC[i].y ? 0.f : exp2f(sc[1])*inv;                           \
        float p2 = MC[i].z ? 0.f : exp2f(sc[2])*inv;                           \
        float p3 = MC[i].w ? 0.f : exp2f(sc[3])*inv;                           \
        *(float4*)(abase + (T)*64 + i*16 + lg*4) = (float4){p0,p1,p2,p3};      \
        uint2 pw2; pw2.x = pk2(p0,p1); pw2.y = pk2(p2,p3);                     \
        *(uint2*)(buf + lr*64 + ((hf*32 + lg*8) ^ swzP)) = pw2;                \
      }                                                                        \
      bf16x8 pa = *(const bf16x8*)(buf + lr*64 + ((lg*16) ^ swzP));            \
      _Pragma("unroll")                                                        \
      for (int dd=0; dd<4; ++dd)                                               \
        cacc[dd] = MFMA(pa, VC[u*4+dd], cacc[dd], 0,0,0);                      \
    }                                                                          \
    __builtin_amdgcn_s_setprio(0);                                             \
    SFENCE();                                                                  \
  }

__global__ __launch_bounds__(256, 4) void k_fattn(
    const bf16* __restrict__ qb, const bf16* __restrict__ kb,
    const bf16* __restrict__ vt, const unsigned char* __restrict__ mask,
    float* __restrict__ attn, bf16* __restrict__ ctx) {
  int lin = blockIdx.x + 16*blockIdx.y;   // 0..1151
  int xcd  = lin & 7;
  int slot = lin >> 3;
  int qt   = slot & 15;
  int bh   = xcd*9 + (slot >> 4);         // bijective remap: head locality per XCD
  int b = bh / H, h = bh - b*H;
  int tid = threadIdx.x, lane = tid & 63, w = tid >> 6;
  int lr = lane & 15, lg = lane >> 4;
  int q0 = qt*64 + w*16;

  __shared__ bf16 Kb[2][8192];      // 2 x 16KB: [128 k][64 dk] swizzled
  __shared__ bf16 pt[4][512];       // per-wave P tile, 1KB
  char* KbL = (char*)&Kb[0][0];
  char* buf = (char*)&pt[w][0];

  const bf16* qbase = qb + ((size_t)bh*S + q0 + lr)*DK + lg*8;
  bf16x8 qa0 = *(const bf16x8*)(qbase);
  bf16x8 qa1 = *(const bf16x8*)(qbase + 32);
  SFENCE();   // keep q loads out of the counted windows

  const char* kg = (const char*)(kb + (size_t)bh*S*DK);
  const char* vg = (const char*)(vt + (size_t)bh*DK*S);
  const unsigned char* mrow = mask + ((size_t)b*S + q0 + lr)*S;
  float* abase = attn + ((size_t)bh*S + q0 + lr)*S;

  // K staging addresses (per-lane global src; wave-uniform LDS base)
  const char* ksrc = kg + w*1024 + lane*16;   // + t*16384 + r*4096
  const int ldsK = w*1024;                    // + buf*16384 + r*4096

  // V direct-read offsets (global pre-swizzle slot^=d&7 within 128B windows)
  int voff[8];
  #pragma unroll
  for (int u=0;u<2;++u)
    #pragma unroll
    for (int dd=0;dd<4;++dd)
      voff[u*4+dd] = (dd*16+lr)*2048 + ((((u*4+lg) ^ (lr&7))) << 4);

  // K fragment read offsets (bf16 idx), swizzle: slot ^ (row&7)
  const int krow = lr*64;
  const int kf0o = krow + ((lg ^ (lr&7))<<3);
  const int kf1o = krow + (((4+lg) ^ (lr&7))<<3);
  const int swzP = (lr & 3) << 4;

  // ================= PASS 1: row sums (no LDS P, no V) =================
  STAGE_K(0, 0);
  SFENCE();
  uchar4 mkc[8], mkn[8];
  #pragma unroll
  for (int i=0;i<8;++i) mkn[i] = *(const uchar4*)(mrow + i*16 + lg*4);
  SFENCE();
  WAITV(8);       // 8 mask loads newer than the 4 K gl16s
  BARRIER();
  SFENCE();

  float sum = 0.f;
  for (int t = 0; t < 8; ++t) {
    const bf16* Kt = (const bf16*)(KbL + (t&1)*16384);
    if (t < 7) { STAGE_K(t+1, (t+1)&1); }
    SFENCE();
    #pragma unroll
    for (int i=0;i<8;++i) mkc[i] = mkn[i];
    if (t < 7) {
      #pragma unroll
      for (int i=0;i<8;++i) mkn[i] = *(const uchar4*)(mrow + (t+1)*128 + i*16 + lg*4);
    }
    SFENCE();
    __builtin_amdgcn_s_setprio(1);
    #pragma unroll
    for (int i=0;i<8;++i) {
      bf16x8 kf0 = *(const bf16x8*)&Kt[i*1024 + kf0o];
      bf16x8 kf1 = *(const bf16x8*)&Kt[i*1024 + kf1o];
      f32x4 sc = {0.f,0.f,0.f,0.f};
      sc = MFMA(kf0, qa0, sc, 0,0,0);
      sc = MFMA(kf1, qa1, sc, 0,0,0);
      sum += mkc[i].x ? 0.f : exp2f(sc[0]);
      sum += mkc[i].y ? 0.f : exp2f(sc[1]);
      sum += mkc[i].z ? 0.f : exp2f(sc[2]);
      sum += mkc[i].w ? 0.f : exp2f(sc[3]);
    }
    __builtin_amdgcn_s_setprio(0);
    SFENCE();
    if (t < 7) { WAITV(8); BARRIER(); SFENCE(); }
  }
  sum += __shfl_xor(sum, 16);
  sum += __shfl_xor(sum, 32);
  float inv = 1.f / sum;

  // ================= PASS 2: normalized attn write + PV =================
  f32x4 cacc[4];
  #pragma unroll
  for (int d=0;d<4;++d) cacc[d] = (f32x4){0.f,0.f,0.f,0.f};
  bf16x8 VA[8], VB[8];
  uchar4 mkA[4], mkB[4];

  STAGE_K(0, 0);
  SFENCE();
  #pragma unroll
  for (int j=0;j<8;++j) VA[j] = *(const bf16x8*)(vg + voff[j]);
  #pragma unroll
  for (int i=0;i<4;++i) mkA[i] = *(const uchar4*)(mrow + i*16 + lg*4);
  SFENCE();
  WAITV(12);      // 8 V + 4 mask newer than the 4 K gl16s
  BARRIER();
  SFENCE();

  for (int t = 0; t < 8; ++t) {
    if (t < 7) { STAGE_K(t+1, (t+1)&1); }
    SFENCE();
    FSUB(2*t,   (t&1)*16384,        VA, VB, mkA, mkB);
    FSUB(2*t+1, (t&1)*16384 + 8192, VB, VA, mkB, mkA);
    if (t < 7) { WAITV(32); BARRIER(); SFENCE(); }  // 2x(8V+4mask+4st) after K gl16s
  }

  // ---- ctx write: lane holds ctx[q=q0+lg*4+r][d*16+lr] (already normalized)
  #pragma unroll
  for (int d=0;d<4;++d)
    #pragma unroll
    for (int r=0;r<4;++r)
      ctx[((size_t)b*S + q0 + lg*4 + r)*DM + h*DK + d*16 + lr] = (bf16)cacc[d][r];
}

// ---------------- layernorm rows of 768 -> d_out
__global__ void k_ln(const float* __restrict__ x, const float* __restrict__ gamma,
                     const float* __restrict__ beta, float* __restrict__ out) {
  int row = blockIdx.x; int tid = threadIdx.x;
  const float* xr = x + (size_t)row*DM;
  float v0 = xr[tid], v1 = xr[tid+256], v2 = xr[tid+512];
  float s = v0+v1+v2, ss = v0*v0+v1*v1+v2*v2;
  #pragma unroll
  for (int off=32; off; off>>=1){ s += __shfl_xor(s,off); ss += __shfl_xor(ss,off); }
  __shared__ float sm[8];
  int w = tid>>6;
  if ((tid&63)==0){ sm[w]=s; sm[4+w]=ss; }
  __syncthreads();
  s = sm[0]+sm[1]+sm[2]+sm[3]; ss = sm[4]+sm[5]+sm[6]+sm[7];
  float mean = s * (1.f/DM);
  float var = ss * (1.f/DM) - mean*mean;
  float rstd = rsqrtf(var + 1e-5f);
  out[(size_t)row*DM + tid]     = (v0-mean)*rstd*gamma[tid]     + beta[tid];
  out[(size_t)row*DM + tid+256] = (v1-mean)*rstd*gamma[tid+256] + beta[tid+256];
  out[(size_t)row*DM + tid+512] = (v2-mean)*rstd*gamma[tid+512] + beta[tid+512];
}

extern "C" void kernel_launch(void* const* d_in, const int* in_sizes, int n_in,
                              void* d_out, int out_size, void* d_ws, size_t ws_size,
                              hipStream_t stream) {
  const float* Q  = (const float*)d_in[0];
  const float* K  = (const float*)d_in[1];
  const float* V  = (const float*)d_in[2];
  const unsigned char* mask = (const unsigned char*)d_in[3];
  const float* Wq = (const float*)d_in[4];
  const float* bq = (const float*)d_in[5];
  const float* Wk = (const float*)d_in[6];
  const float* bk = (const float*)d_in[7];
  const float* Wv = (const float*)d_in[8];
  const float* bv = (const float*)d_in[9];
  const float* Wo = (const float*)d_in[10];
  const float* bo = (const float*)d_in[11];
  const float* gamma = (const float*)d_in[12];
  const float* beta  = (const float*)d_in[13];

  char* ws = (char*)d_ws;
  bf16* wt  = (bf16*)(ws + 0);            // [4][768][768]        4,718,592 B
  bf16* xb  = (bf16*)(ws + 4718592);      // [3][6144][768]      28,311,552 B
  bf16* qb  = (bf16*)(ws + 33030144);     // [72][1024][64] q*QSCALE
  bf16* kb  = (bf16*)(ws + 42467328);     // [72][1024][64] swz   9,437,184 B
  bf16* vt  = (bf16*)(ws + 51904512);     // [72][64][1024] swz   9,437,184 B
  bf16* ctx = (bf16*)(ws + 61341696);     // [6][1024][768]       9,437,184 B
  float* x  = (float*)(ws + 4718592);     // alias xb (dead after k_proj)

  float* out  = (float*)d_out;                   // [6][1024][768]
  float* attn = out + (size_t)B*S*DM;            // [6][12][1024][1024]

  k_prep  <<<dim3(2304,7),  256, 0, stream>>>(Q,K,V,Wq,Wk,Wv,Wo,xb,wt);
  k_proj  <<<dim3(48,6,3),  256, 0, stream>>>(xb,wt,bq,bk,bv,qb,kb,vt);
  k_fattn <<<dim3(16,BH),   256, 0, stream>>>(qb,kb,vt,mask,attn,ctx);
  k_oproj <<<dim3(48,6),    256, 0, stream>>>(ctx, wt + (size_t)3*DM*DM, bo, Q, x);
  k_ln    <<<dim3(M),       256, 0, stream>>>(x,gamma,beta,out);
}

// Round 12
// 246.591 us; speedup vs baseline: 2.5306x; 1.5504x over previous
//
#include <hip/hip_runtime.h>
#include <hip/hip_bf16.h>

#define B 6
#define S 1024
#define H 12
#define DK 64
#define DM 768
#define M (B*S)      // 6144
#define BH (B*H)     // 72

typedef __bf16 bf16;
typedef __attribute__((ext_vector_type(8))) __bf16 bf16x8;
typedef __attribute__((ext_vector_type(4))) float f32x4;

#define MFMA __builtin_amdgcn_mfma_f32_16x16x32_bf16

// 0.125 * log2(e): folded into q so softmax exp becomes a bare v_exp_f32 (2^x)
#define QSCALE 0.18033688011112042f

// single-instruction 2^x (v_exp_f32); avoids __ocml libcall paths
__device__ __forceinline__ float ex2(float x) {
  float r;
  asm("v_exp_f32 %0, %1" : "=v"(r) : "v"(x));
  return r;
}

// lgkm-only barrier: staged LDS visible, but don't drain global stores/loads
__device__ __forceinline__ void lds_barrier() {
  asm volatile("s_waitcnt lgkmcnt(0)" ::: "memory");
  __builtin_amdgcn_s_barrier();
}

// ---------------- prep: input f32->bf16 convert (z<3) + weight transpose (z>=3)
__global__ void k_prep(const float* __restrict__ Q, const float* __restrict__ K,
                       const float* __restrict__ V,
                       const float* __restrict__ Wq, const float* __restrict__ Wk,
                       const float* __restrict__ Wv, const float* __restrict__ Wo,
                       bf16* __restrict__ xb, bf16* __restrict__ wt) {
  int z = blockIdx.y;
  if (z < 3) {
    const float* X = z==0?Q : z==1?K : V;
    size_t i = ((size_t)blockIdx.x*256 + threadIdx.x)*8;
    float4 a = *(const float4*)(X + i);
    float4 b = *(const float4*)(X + i + 4);
    bf16x8 r;
    r[0]=(bf16)a.x; r[1]=(bf16)a.y; r[2]=(bf16)a.z; r[3]=(bf16)a.w;
    r[4]=(bf16)b.x; r[5]=(bf16)b.y; r[6]=(bf16)b.z; r[7]=(bf16)b.w;
    *(bf16x8*)(xb + (size_t)z*M*DM + i) = r;
  } else {
    int zz = z - 3;
    const float* W = zz==0?Wq : zz==1?Wk : zz==2?Wv : Wo;
    int idx = blockIdx.x*256 + threadIdx.x;   // 0..768*768-1
    int k = idx / DM, n = idx % DM;
    wt[(size_t)zz*DM*DM + (size_t)n*DM + k] = (bf16)W[idx];
  }
}

// ======== GEMM bodies (round-8 proven): 128x128 tile, BK=32, dbuf LDS, reg-staged.
// LDS tile [128 rows][32 k] bf16, read-swizzled: chunk' = chunk ^ ((row>>1)&3).
// ds_write side is LINEAR; swizzle applied by permuting the GLOBAL source chunks.

// ---------------- QKV projection; epilogue scatters q/k/v (kb,vt pre-swizzled;
// q pre-scaled by QSCALE)
__global__ __launch_bounds__(256, 3) void k_proj(
    const bf16* __restrict__ xb, const bf16* __restrict__ wt,
    const float* __restrict__ bq, const float* __restrict__ bk,
    const float* __restrict__ bv,
    bf16* __restrict__ qb, bf16* __restrict__ kb, bf16* __restrict__ vt) {
  int z = blockIdx.z;
  const bf16* X    = xb + (size_t)z*M*DM;
  const float* bias = z==0?bq : z==1?bk : bv;
  const bf16* Wt = wt + (size_t)z*DM*DM;
  int tid = threadIdx.x, lane = tid & 63, w = tid >> 6;
  int wr = w >> 1, wc = w & 1;
  int lr = lane & 15, lg = lane >> 4;
  int m0 = blockIdx.x*128;
  int n0 = blockIdx.y*128;

  __shared__ bf16 As[2][128*32];
  __shared__ bf16 Bs[2][128*32];

  const int srow = tid >> 1;
  const int c0   = (tid & 1) * 2;             // dst chunk pair (16B chunks)
  const int f    = (srow >> 1) & 3;           // swizzle class of this row
  const int sc   = (c0 ^ f) & ~1;             // src chunk pair base (even)
  const bool sw  = (f & 1);                   // swap the two 16B regs
  const bf16* asrc = X  + (size_t)(m0 + srow)*DM + sc*8;
  const bf16* bsrc = Wt + (size_t)(n0 + srow)*DM + sc*8;
  const int dst0 = srow*32 + c0*8;            // bf16 idx (linear)

  const int fs = (lr >> 1) & 3;
  const int fchunk = (lg ^ fs) * 8;

  f32x4 acc[4][4];
  #pragma unroll
  for (int i=0;i<4;++i)
    #pragma unroll
    for (int j=0;j<4;++j) acc[i][j] = (f32x4){0.f,0.f,0.f,0.f};

  { // prologue: stage tile 0
    bf16x8 a0 = *(const bf16x8*)(asrc);
    bf16x8 a1 = *(const bf16x8*)(asrc + 8);
    bf16x8 b0 = *(const bf16x8*)(bsrc);
    bf16x8 b1 = *(const bf16x8*)(bsrc + 8);
    *(bf16x8*)&As[0][dst0]     = sw ? a1 : a0;
    *(bf16x8*)&As[0][dst0 + 8] = sw ? a0 : a1;
    *(bf16x8*)&Bs[0][dst0]     = sw ? b1 : b0;
    *(bf16x8*)&Bs[0][dst0 + 8] = sw ? b0 : b1;
  }
  lds_barrier();

  for (int t = 0; t < 24; ++t) {
    int cur = t & 1;
    bf16x8 pa0, pa1, pb0, pb1;
    if (t < 23) {
      int k0 = (t+1)*32;
      pa0 = *(const bf16x8*)(asrc + k0);
      pa1 = *(const bf16x8*)(asrc + k0 + 8);
      pb0 = *(const bf16x8*)(bsrc + k0);
      pb1 = *(const bf16x8*)(bsrc + k0 + 8);
    }
    bf16x8 af[4], bfr[4];
    #pragma unroll
    for (int mi=0;mi<4;++mi) af[mi]  = *(const bf16x8*)&As[cur][(wr*64 + mi*16 + lr)*32 + fchunk];
    #pragma unroll
    for (int ni=0;ni<4;++ni) bfr[ni] = *(const bf16x8*)&Bs[cur][(wc*64 + ni*16 + lr)*32 + fchunk];
    #pragma unroll
    for (int mi=0;mi<4;++mi)
      #pragma unroll
      for (int ni=0;ni<4;++ni)
        acc[mi][ni] = MFMA(af[mi], bfr[ni], acc[mi][ni], 0,0,0);
    if (t < 23) {
      *(bf16x8*)&As[cur^1][dst0]     = sw ? pa1 : pa0;
      *(bf16x8*)&As[cur^1][dst0 + 8] = sw ? pa0 : pa1;
      *(bf16x8*)&Bs[cur^1][dst0]     = sw ? pb1 : pb0;
      *(bf16x8*)&Bs[cur^1][dst0 + 8] = sw ? pb0 : pb1;
      lds_barrier();
    }
  }

  int mw = m0 + wr*64, nw = n0 + wc*64;
  #pragma unroll
  for (int ni=0;ni<4;++ni) {
    int n = nw + ni*16 + lr;
    float bs = bias[n];
    int h = n >> 6, d = n & 63;
    #pragma unroll
    for (int mi=0;mi<4;++mi)
      #pragma unroll
      for (int r=0;r<4;++r) {
        int m = mw + mi*16 + lg*4 + r;
        int bb = m >> 10, s = m & 1023;
        float val = acc[mi][ni][r] + bs;
        if (z == 0) {
          qb[((size_t)(bb*H + h)*S + s)*DK + d] = (bf16)(val * QSCALE);
        } else if (z == 1) {
          int dsw = ((((d>>3) ^ (s&7))) << 3) | (d&7);          // slot ^= s&7
          kb[((size_t)(bb*H + h)*S + s)*DK + dsw] = (bf16)val;
        } else {
          int ssw = (s & ~63) | ((((s&63)>>3) ^ (d&7)) << 3) | (s&7); // slot ^= d&7
          vt[((size_t)(bb*H + h)*DK + d)*S + ssw] = (bf16)val;
        }
      }
  }
}

// ---------------- out projection + bias + residual -> x (f32), same tiled body
__global__ __launch_bounds__(256, 3) void k_oproj(
    const bf16* __restrict__ ctx, const bf16* __restrict__ wto,
    const float* __restrict__ bo, const float* __restrict__ res,
    float* __restrict__ x) {
  int tid = threadIdx.x, lane = tid & 63, w = tid >> 6;
  int wr = w >> 1, wc = w & 1;
  int lr = lane & 15, lg = lane >> 4;
  int m0 = blockIdx.x*128;
  int n0 = blockIdx.y*128;

  __shared__ bf16 As[2][128*32];
  __shared__ bf16 Bs[2][128*32];

  const int srow = tid >> 1;
  const int c0   = (tid & 1) * 2;
  const int f    = (srow >> 1) & 3;
  const int sc   = (c0 ^ f) & ~1;
  const bool sw  = (f & 1);
  const bf16* asrc = ctx + (size_t)(m0 + srow)*DM + sc*8;
  const bf16* bsrc = wto + (size_t)(n0 + srow)*DM + sc*8;
  const int dst0 = srow*32 + c0*8;
  const int fs = (lr >> 1) & 3;
  const int fchunk = (lg ^ fs) * 8;

  f32x4 acc[4][4];
  #pragma unroll
  for (int i=0;i<4;++i)
    #pragma unroll
    for (int j=0;j<4;++j) acc[i][j] = (f32x4){0.f,0.f,0.f,0.f};

  {
    bf16x8 a0 = *(const bf16x8*)(asrc);
    bf16x8 a1 = *(const bf16x8*)(asrc + 8);
    bf16x8 b0 = *(const bf16x8*)(bsrc);
    bf16x8 b1 = *(const bf16x8*)(bsrc + 8);
    *(bf16x8*)&As[0][dst0]     = sw ? a1 : a0;
    *(bf16x8*)&As[0][dst0 + 8] = sw ? a0 : a1;
    *(bf16x8*)&Bs[0][dst0]     = sw ? b1 : b0;
    *(bf16x8*)&Bs[0][dst0 + 8] = sw ? b0 : b1;
  }
  lds_barrier();

  for (int t = 0; t < 24; ++t) {
    int cur = t & 1;
    bf16x8 pa0, pa1, pb0, pb1;
    if (t < 23) {
      int k0 = (t+1)*32;
      pa0 = *(const bf16x8*)(asrc + k0);
      pa1 = *(const bf16x8*)(asrc + k0 + 8);
      pb0 = *(const bf16x8*)(bsrc + k0);
      pb1 = *(const bf16x8*)(bsrc + k0 + 8);
    }
    bf16x8 af[4], bfr[4];
    #pragma unroll
    for (int mi=0;mi<4;++mi) af[mi]  = *(const bf16x8*)&As[cur][(wr*64 + mi*16 + lr)*32 + fchunk];
    #pragma unroll
    for (int ni=0;ni<4;++ni) bfr[ni] = *(const bf16x8*)&Bs[cur][(wc*64 + ni*16 + lr)*32 + fchunk];
    #pragma unroll
    for (int mi=0;mi<4;++mi)
      #pragma unroll
      for (int ni=0;ni<4;++ni)
        acc[mi][ni] = MFMA(af[mi], bfr[ni], acc[mi][ni], 0,0,0);
    if (t < 23) {
      *(bf16x8*)&As[cur^1][dst0]     = sw ? pa1 : pa0;
      *(bf16x8*)&As[cur^1][dst0 + 8] = sw ? pa0 : pa1;
      *(bf16x8*)&Bs[cur^1][dst0]     = sw ? pb1 : pb0;
      *(bf16x8*)&Bs[cur^1][dst0 + 8] = sw ? pb0 : pb1;
      lds_barrier();
    }
  }

  int mw = m0 + wr*64, nw = n0 + wc*64;
  #pragma unroll
  for (int ni=0;ni<4;++ni) {
    int n = nw + ni*16 + lr;
    float bb = bo[n];
    #pragma unroll
    for (int mi=0;mi<4;++mi)
      #pragma unroll
      for (int r=0;r<4;++r) {
        int m = mw + mi*16 + lg*4 + r;
        x[(size_t)m*DM + n] = acc[mi][ni][r] + bb + res[(size_t)m*DM + n];
      }
  }
}

__device__ __forceinline__ unsigned pk2(float a, float b) {
  union { bf16 h[2]; unsigned u; } x;
  x.h[0] = (bf16)a; x.h[1] = (bf16)b;
  return x.u;
}

// ---------------- fused attention (round-8 structure, exp via v_exp_f32):
// Block = (bh, 64 q-rows), 4 waves x 16 rows. K/V tiles (64k x 64dk) double-
// buffered in LDS, staged by reg round-trip; lgkm-only barriers.
// Swapped QK^T: mfma(A=K, B=Q) -> lane(lr,lg) holds p[k=lg*4+r][q=lr].
__global__ __launch_bounds__(256, 4) void k_fattn(
    const bf16* __restrict__ qb, const bf16* __restrict__ kb,
    const bf16* __restrict__ vt, const unsigned char* __restrict__ mask,
    float* __restrict__ attn, bf16* __restrict__ ctx) {
  int lin = blockIdx.x + 16*blockIdx.y;   // 0..1151
  int xcd  = lin & 7;
  int slot = lin >> 3;
  int qt   = slot & 15;
  int bh   = xcd*9 + (slot >> 4);         // bijective remap: head locality per XCD
  int b = bh / H, h = bh - b*H;
  int tid = threadIdx.x, lane = tid & 63, w = tid >> 6;
  int lr = lane & 15, lg = lane >> 4;
  int q0 = qt*64 + w*16;

  __shared__ bf16 Kb[2][4096];      // [64 k][64 dk] swizzled, 8KB each
  __shared__ bf16 Vb[2][4096];      // [64 dk][64 k] swizzled, 8KB each
  __shared__ bf16 pt[4][2][512];    // per-wave P ping-pong tiles, 1KB each

  const bf16* qbase = qb + ((size_t)bh*S + q0 + lr)*DK + lg*8;
  bf16x8 qa0 = *(const bf16x8*)(qbase);
  bf16x8 qa1 = *(const bf16x8*)(qbase + 32);

  const char* kg = (const char*)(kb + (size_t)bh*S*DK);   // 8KB contiguous per tile
  const char* vg = (const char*)(vt + (size_t)bh*DK*S);   // rows 2048B apart
  const unsigned char* mrow = mask + ((size_t)b*S + q0 + lr)*S;
  float* abase = attn + ((size_t)bh*S + q0 + lr)*S;

  const int koff0 = w*2048 + lane*16, koff1 = koff0 + 1024;
  const int kd0 = w*1024 + lane*8,    kd1 = kd0 + 512;
  const int vrow0 = w*16 + (lane>>3), vrow1 = vrow0 + 8;
  const int vcb = (lane&7)*16;
  const int vd0 = vrow0*64 + (lane&7)*8, vd1 = vd0 + 512;

  const int krow = lr*64;
  const int kf0o = krow + ((lg ^ (lr&7))<<3);
  const int kf1o = krow + (((4+lg) ^ (lr&7))<<3);
  const int swz  = (lr & 3) << 4;

  // ================= PASS 1: row sums =================
  {
    bf16x8 a0 = *(const bf16x8*)(kg + koff0);
    bf16x8 a1 = *(const bf16x8*)(kg + koff1);
    *(bf16x8*)&Kb[0][kd0] = a0;
    *(bf16x8*)&Kb[0][kd1] = a1;
  }
  uchar4 mkn[4];
  #pragma unroll
  for (int i=0;i<4;++i) mkn[i] = *(const uchar4*)(mrow + i*16 + lg*4);
  lds_barrier();

  float sum = 0.f;
  for (int t = 0; t < 16; ++t) {
    int cur = t & 1;
    uchar4 mkc[4];
    #pragma unroll
    for (int i=0;i<4;++i) mkc[i] = mkn[i];
    bf16x8 kn0, kn1;
    if (t < 15) {
      kn0 = *(const bf16x8*)(kg + (t+1)*8192 + koff0);
      kn1 = *(const bf16x8*)(kg + (t+1)*8192 + koff1);
      #pragma unroll
      for (int i=0;i<4;++i) mkn[i] = *(const uchar4*)(mrow + (t+1)*64 + i*16 + lg*4);
    }
    #pragma unroll
    for (int i=0;i<4;++i) {
      bf16x8 kf0 = *(const bf16x8*)&Kb[cur][i*1024 + kf0o];
      bf16x8 kf1 = *(const bf16x8*)&Kb[cur][i*1024 + kf1o];
      f32x4 sc = {0.f,0.f,0.f,0.f};
      sc = MFMA(kf0, qa0, sc, 0,0,0);
      sc = MFMA(kf1, qa1, sc, 0,0,0);
      sum += mkc[i].x ? 0.f : ex2(sc[0]);
      sum += mkc[i].y ? 0.f : ex2(sc[1]);
      sum += mkc[i].z ? 0.f : ex2(sc[2]);
      sum += mkc[i].w ? 0.f : ex2(sc[3]);
    }
    if (t < 15) {
      *(bf16x8*)&Kb[cur^1][kd0] = kn0;
      *(bf16x8*)&Kb[cur^1][kd1] = kn1;
    }
    lds_barrier();
  }
  sum += __shfl_xor(sum, 16);
  sum += __shfl_xor(sum, 32);
  float inv = 1.f / sum;

  // ================= PASS 2: attn write + PV =================
  f32x4 cacc[4];
  #pragma unroll
  for (int d=0;d<4;++d) cacc[d] = (f32x4){0.f,0.f,0.f,0.f};

  {
    bf16x8 a0 = *(const bf16x8*)(kg + koff0);
    bf16x8 a1 = *(const bf16x8*)(kg + koff1);
    bf16x8 b0 = *(const bf16x8*)(vg + (size_t)vrow0*2048 + vcb);
    bf16x8 b1 = *(const bf16x8*)(vg + (size_t)vrow1*2048 + vcb);
    *(bf16x8*)&Kb[0][kd0] = a0;
    *(bf16x8*)&Kb[0][kd1] = a1;
    *(bf16x8*)&Vb[0][vd0] = b0;
    *(bf16x8*)&Vb[0][vd1] = b1;
    #pragma unroll
    for (int i=0;i<4;++i) mkn[i] = *(const uchar4*)(mrow + i*16 + lg*4);
  }
  lds_barrier();

  for (int t = 0; t < 16; ++t) {
    int cur = t & 1;
    uchar4 mkc[4];
    #pragma unroll
    for (int i=0;i<4;++i) mkc[i] = mkn[i];
    bf16x8 kn0, kn1, vn0, vn1;
    if (t < 15) {
      kn0 = *(const bf16x8*)(kg + (t+1)*8192 + koff0);
      kn1 = *(const bf16x8*)(kg + (t+1)*8192 + koff1);
      vn0 = *(const bf16x8*)(vg + (size_t)vrow0*2048 + (t+1)*128 + vcb);
      vn1 = *(const bf16x8*)(vg + (size_t)vrow1*2048 + (t+1)*128 + vcb);
      #pragma unroll
      for (int i=0;i<4;++i) mkn[i] = *(const uchar4*)(mrow + (t+1)*64 + i*16 + lg*4);
    }
    #pragma unroll
    for (int u = 0; u < 2; ++u) {
      char* buf = (char*)&pt[w][u][0];
      #pragma unroll
      for (int half = 0; half < 2; ++half) {
        int i = u*2 + half;
        bf16x8 kf0 = *(const bf16x8*)&Kb[cur][i*1024 + kf0o];
        bf16x8 kf1 = *(const bf16x8*)&Kb[cur][i*1024 + kf1o];
        f32x4 sc = {0.f,0.f,0.f,0.f};
        sc = MFMA(kf0, qa0, sc, 0,0,0);
        sc = MFMA(kf1, qa1, sc, 0,0,0);
        float p0 = mkc[i].x ? 0.f : ex2(sc[0])*inv;
        float p1 = mkc[i].y ? 0.f : ex2(sc[1])*inv;
        float p2 = mkc[i].z ? 0.f : ex2(sc[2])*inv;
        float p3 = mkc[i].w ? 0.f : ex2(sc[3])*inv;
        *(float4*)(abase + t*64 + i*16 + lg*4) = (float4){p0,p1,p2,p3};
        uint2 pw2; pw2.x = pk2(p0,p1); pw2.y = pk2(p2,p3);
        *(uint2*)(buf + lr*64 + ((half*32 + lg*8) ^ swz)) = pw2;
      }
      bf16x8 pa = *(const bf16x8*)(buf + lr*64 + ((lg*16) ^ swz));
      #pragma unroll
      for (int dd=0; dd<4; ++dd) {
        bf16x8 vf = *(const bf16x8*)&Vb[cur][dd*1024 + lr*64 + ((((u*4+lg) ^ (lr&7)))<<3)];
        cacc[dd] = MFMA(pa, vf, cacc[dd], 0,0,0);
      }
    }
    if (t < 15) {
      *(bf16x8*)&Kb[cur^1][kd0] = kn0;
      *(bf16x8*)&Kb[cur^1][kd1] = kn1;
      *(bf16x8*)&Vb[cur^1][vd0] = vn0;
      *(bf16x8*)&Vb[cur^1][vd1] = vn1;
    }
    lds_barrier();
  }

  #pragma unroll
  for (int d=0;d<4;++d)
    #pragma unroll
    for (int r=0;r<4;++r)
      ctx[((size_t)b*S + q0 + lg*4 + r)*DM + h*DK + d*16 + lr] = (bf16)cacc[d][r];
}

// ---------------- layernorm rows of 768 -> d_out
__global__ void k_ln(const float* __restrict__ x, const float* __restrict__ gamma,
                     const float* __restrict__ beta, float* __restrict__ out) {
  int row = blockIdx.x; int tid = threadIdx.x;
  const float* xr = x + (size_t)row*DM;
  float v0 = xr[tid], v1 = xr[tid+256], v2 = xr[tid+512];
  float s = v0+v1+v2, ss = v0*v0+v1*v1+v2*v2;
  #pragma unroll
  for (int off=32; off; off>>=1){ s += __shfl_xor(s,off); ss += __shfl_xor(ss,off); }
  __shared__ float sm[8];
  int w = tid>>6;
  if ((tid&63)==0){ sm[w]=s; sm[4+w]=ss; }
  __syncthreads();
  s = sm[0]+sm[1]+sm[2]+sm[3]; ss = sm[4]+sm[5]+sm[6]+sm[7];
  float mean = s * (1.f/DM);
  float var = ss * (1.f/DM) - mean*mean;
  float rstd = rsqrtf(var + 1e-5f);
  out[(size_t)row*DM + tid]     = (v0-mean)*rstd*gamma[tid]     + beta[tid];
  out[(size_t)row*DM + tid+256] = (v1-mean)*rstd*gamma[tid+256] + beta[tid+256];
  out[(size_t)row*DM + tid+512] = (v2-mean)*rstd*gamma[tid+512] + beta[tid+512];
}

extern "C" void kernel_launch(void* const* d_in, const int* in_sizes, int n_in,
                              void* d_out, int out_size, void* d_ws, size_t ws_size,
                              hipStream_t stream) {
  const float* Q  = (const float*)d_in[0];
  const float* K  = (const float*)d_in[1];
  const float* V  = (const float*)d_in[2];
  const unsigned char* mask = (const unsigned char*)d_in[3];
  const float* Wq = (const float*)d_in[4];
  const float* bq = (const float*)d_in[5];
  const float* Wk = (const float*)d_in[6];
  const float* bk = (const float*)d_in[7];
  const float* Wv = (const float*)d_in[8];
  const float* bv = (const float*)d_in[9];
  const float* Wo = (const float*)d_in[10];
  const float* bo = (const float*)d_in[11];
  const float* gamma = (const float*)d_in[12];
  const float* beta  = (const float*)d_in[13];

  char* ws = (char*)d_ws;
  bf16* wt  = (bf16*)(ws + 0);            // [4][768][768]        4,718,592 B
  bf16* xb  = (bf16*)(ws + 4718592);      // [3][6144][768]      28,311,552 B
  bf16* qb  = (bf16*)(ws + 33030144);     // [72][1024][64] q*QSCALE
  bf16* kb  = (bf16*)(ws + 42467328);     // [72][1024][64] swz   9,437,184 B
  bf16* vt  = (bf16*)(ws + 51904512);     // [72][64][1024] swz   9,437,184 B
  bf16* ctx = (bf16*)(ws + 61341696);     // [6][1024][768]       9,437,184 B
  float* x  = (float*)(ws + 4718592);     // alias xb (dead after k_proj)

  float* out  = (float*)d_out;                   // [6][1024][768]
  float* attn = out + (size_t)B*S*DM;            // [6][12][1024][1024]

  k_prep  <<<dim3(2304,7),  256, 0, stream>>>(Q,K,V,Wq,Wk,Wv,Wo,xb,wt);
  k_proj  <<<dim3(48,6,3),  256, 0, stream>>>(xb,wt,bq,bk,bv,qb,kb,vt);
  k_fattn <<<dim3(16,BH),   256, 0, stream>>>(qb,kb,vt,mask,attn,ctx);
  k_oproj <<<dim3(48,6),    256, 0, stream>>>(ctx, wt + (size_t)3*DM*DM, bo, Q, x);
  k_ln    <<<dim3(M),       256, 0, stream>>>(x,gamma,beta,out);
}